// Round 6
// baseline (2232.204 us; speedup 1.0000x reference)
//
#include <hip/hip_runtime.h>
#include <hip/hip_bf16.h>

#define NU 160000
#define NM 60000
#define DD 64
#define NE 5000000
#define NL 200000

// res = x + (1/2 + 1/3 + 1/4) * agg = x + (13/12)*agg  (all layers propagate layer-0)
#define COEF (13.0f / 12.0f)

// ---- phase-major grouped layout ----
// u-side: wave owns GU=20 users; movie sources split in NPH_U=4 slices (1.92MB of y_m each)
// m-side: wave owns GM=8 movies;  user sources split in NPH_M=10 slices (2.0MB of y_u each)
// vk = (group*NPH + h)*G + dest_local ; pay sorted by vk; gather loops h OUTER.
// Gather executes 4 edges per wave-instruction: 4 groups x 16 lanes, lane loads 8B (4 bf16 cols).
#define GU 20
#define NPH_U 4
#define UDIV 15000                      // h_u = movie / 15000 -> 0..3
#define NGRP_U (NU / GU)                // 8000 (exact)
#define NVK_U (NGRP_U * NPH_U * GU)     // 640000
#define NBK_U ((NVK_U + 1023) >> 10)    // 625

#define GM 8
#define NPH_M 10
#define MDIV 16000                      // h_m = user / 16000 -> 0..9
#define NGRP_M (NM / GM)                // 7500 (exact)
#define NVK_M (NGRP_M * NPH_M * GM)     // 600000
#define NBK_M ((NVK_M + 1023) >> 10)    // 586

#define VB_U 16   // movie id fits 16 bits
#define VB_M 18   // user id fits 18 bits
#define BS 1024   // virtual keys per build bucket

// ---------------- pass A: bucket counts only ----------------

#define CEC 16   // edges/thread

__device__ __forceinline__ int vk_u_of(int u, int m) {
    return ((u / GU) * NPH_U + m / UDIV) * GU + (u % GU);
}
__device__ __forceinline__ int vk_m_of(int m, int u) {
    return (((m >> 3) * NPH_M) + u / MDIV) * GM + (m & 7);
}

__global__ void bucket_count_kernel(const int* __restrict__ ef, const int* __restrict__ et,
                                    int* __restrict__ gbh_u, int* __restrict__ gbh_m) {
    __shared__ int bhu[NBK_U], bhm[NBK_M];
    int tid = threadIdx.x;
    for (int i = tid; i < NBK_U; i += 256) bhu[i] = 0;
    for (int i = tid; i < NBK_M; i += 256) bhm[i] = 0;
    __syncthreads();
    int base = (blockIdx.x * 256 + tid) * CEC;
    if (base < NE) {   // NE % 16 == 0 -> all-or-none
        const int4* f4 = (const int4*)(ef + base);
        const int4* t4 = (const int4*)(et + base);
        #pragma unroll
        for (int q = 0; q < CEC / 4; q++) {
            int4 ff = f4[q]; int4 tt = t4[q];
            atomicAdd(&bhm[vk_m_of(ff.x, tt.x) >> 10], 1); atomicAdd(&bhu[vk_u_of(tt.x, ff.x) >> 10], 1);
            atomicAdd(&bhm[vk_m_of(ff.y, tt.y) >> 10], 1); atomicAdd(&bhu[vk_u_of(tt.y, ff.y) >> 10], 1);
            atomicAdd(&bhm[vk_m_of(ff.z, tt.z) >> 10], 1); atomicAdd(&bhu[vk_u_of(tt.z, ff.z) >> 10], 1);
            atomicAdd(&bhm[vk_m_of(ff.w, tt.w) >> 10], 1); atomicAdd(&bhu[vk_u_of(tt.w, ff.w) >> 10], 1);
        }
    }
    __syncthreads();
    for (int i = tid; i < NBK_U; i += 256) if (bhu[i]) atomicAdd(&gbh_u[i], bhu[i]);
    for (int i = tid; i < NBK_M; i += 256) if (bhm[i]) atomicAdd(&gbh_m[i], bhm[i]);
}

// ---------------- small exclusive scan (n <= 1024); out[n]=total; cursor copy ----------------

__global__ void scan_small_kernel(const int* __restrict__ in, int* __restrict__ out,
                                  int* __restrict__ cur, int n) {
    __shared__ int buf[256];
    int tid = threadIdx.x;
    int idx = tid * 4;
    int v0 = (idx + 0 < n) ? in[idx + 0] : 0;
    int v1 = (idx + 1 < n) ? in[idx + 1] : 0;
    int v2 = (idx + 2 < n) ? in[idx + 2] : 0;
    int v3 = (idx + 3 < n) ? in[idx + 3] : 0;
    int s = v0 + v1 + v2 + v3;
    buf[tid] = s;
    __syncthreads();
    for (int off = 1; off < 256; off <<= 1) {
        int t = (tid >= off) ? buf[tid - off] : 0;
        __syncthreads();
        buf[tid] += t;
        __syncthreads();
    }
    int p = buf[tid] - s;
    if (idx + 0 < n) { out[idx + 0] = p; if (cur) cur[idx + 0] = p; p += v0; }
    if (idx + 1 < n) { out[idx + 1] = p; if (cur) cur[idx + 1] = p; p += v1; }
    if (idx + 2 < n) { out[idx + 2] = p; if (cur) cur[idx + 2] = p; p += v2; }
    if (idx + 3 < n) { out[idx + 3] = p; if (cur) cur[idx + 3] = p; p += v3; }
    if (tid == 255) out[n] = buf[255];
}

// ---------------- coarse partition into bucket-grouped staging (packed int32) ----------------
// stage entry = ((vk & 1023) << valbits) | src

#define PEC 16   // edges/thread; 4096/block

__global__ void partition_kernel(const int* __restrict__ key, const int* __restrict__ val,
                                 int* __restrict__ bcur, int* __restrict__ stage,
                                 int nb, int valbits, int mode) {
    __shared__ int lh[1024];
    __shared__ int lbase[1024];
    int tid = threadIdx.x;
    for (int i = tid; i < nb; i += 256) lh[i] = 0;
    __syncthreads();
    int base = (blockIdx.x * 256 + tid) * PEC;
    int lk_[PEC], v_[PEC], br_[PEC];
    bool act = base < NE;   // NE % 16 == 0 -> all-or-none
    if (act) {
        int k_[PEC];
        const int4* k4 = (const int4*)(key + base);
        const int4* v4 = (const int4*)(val + base);
        #pragma unroll
        for (int q = 0; q < PEC / 4; q++) {
            int4 kk = k4[q]; int4 vv = v4[q];
            k_[q * 4 + 0] = kk.x; k_[q * 4 + 1] = kk.y; k_[q * 4 + 2] = kk.z; k_[q * 4 + 3] = kk.w;
            v_[q * 4 + 0] = vv.x; v_[q * 4 + 1] = vv.y; v_[q * 4 + 2] = vv.z; v_[q * 4 + 3] = vv.w;
        }
        #pragma unroll
        for (int q = 0; q < PEC; q++) {
            int vk = (mode == 0) ? vk_u_of(k_[q], v_[q]) : vk_m_of(k_[q], v_[q]);
            lk_[q] = vk & 1023;
            int b = vk >> 10;
            int r = atomicAdd(&lh[b], 1);       // rank within (block,bucket) < 4096
            br_[q] = (b << 13) | r;
        }
    }
    __syncthreads();
    for (int i = tid; i < nb; i += 256) lbase[i] = lh[i] ? atomicAdd(&bcur[i], lh[i]) : 0;
    __syncthreads();
    if (act) {
        #pragma unroll
        for (int q = 0; q < PEC; q++) {
            int b = br_[q] >> 13;
            int r = br_[q] & 8191;
            stage[lbase[b] + r] = (lk_[q] << valbits) | v_[q];
        }
    }
}

// ---------------- per-bucket build: rp+pay over virtual keys, all in LDS ----------------

__global__ void build_kernel(const int* __restrict__ stage, const int* __restrict__ bo,
                             int* __restrict__ rp, int* __restrict__ pay,
                             int n, int valbits) {
    __shared__ int cnt[BS];
    __shared__ int tmp[BS];
    int b = blockIdx.x;
    int tid = threadIdx.x;
    int base = b << 10;
    int nn = min(BS, n - base);
    int vmask = (1 << valbits) - 1;
    int s0 = bo[b];
    int s1 = bo[b + 1];

    for (int i = tid; i < BS; i += 256) cnt[i] = 0;
    __syncthreads();
    for (int e = s0 + tid; e < s1; e += 256)
        atomicAdd(&cnt[stage[e] >> valbits], 1);
    __syncthreads();
    int ov[4];
    #pragma unroll
    for (int q = 0; q < 4; q++) ov[q] = cnt[tid + q * 256];
    for (int off = 1; off < BS; off <<= 1) {
        int t[4];
        #pragma unroll
        for (int q = 0; q < 4; q++) {
            int i = tid + q * 256;
            t[q] = (i >= off) ? cnt[i - off] : 0;
        }
        __syncthreads();
        #pragma unroll
        for (int q = 0; q < 4; q++) cnt[tid + q * 256] += t[q];
        __syncthreads();
    }
    #pragma unroll
    for (int q = 0; q < 4; q++) {
        int i = tid + q * 256;
        int excl = cnt[i] - ov[q];
        tmp[i] = s0 + excl;
        if (i < nn) rp[base + i] = s0 + excl;
    }
    if (b == 0 && tid == 0) rp[n] = NE;
    __syncthreads();
    for (int e = s0 + tid; e < s1; e += 256) {
        int p = stage[e];
        int pos = atomicAdd(&tmp[p >> valbits], 1);
        pay[pos] = p & vmask;
    }
}

// ---------------- inv kernels (degree = sum of run lengths across phases) ----------------

__global__ void inv_u_kernel(const int* __restrict__ rp, float* __restrict__ inv) {
    int u = blockIdx.x * blockDim.x + threadIdx.x;
    if (u < NU) {
        int g = u / GU, i = u % GU;
        int d = 0;
        #pragma unroll
        for (int h = 0; h < NPH_U; h++) {
            int vk = (g * NPH_U + h) * GU + i;
            d += rp[vk + 1] - rp[vk];
        }
        inv[u] = (d > 0) ? rsqrtf((float)d) : 0.0f;
    }
}

__global__ void inv_m_kernel(const int* __restrict__ rp, float* __restrict__ inv) {
    int m = blockIdx.x * blockDim.x + threadIdx.x;
    if (m < NM) {
        int g = m >> 3, i = m & 7;
        int d = 0;
        #pragma unroll
        for (int h = 0; h < NPH_M; h++) {
            int vk = (g * NPH_M + h) * GM + i;
            d += rp[vk + 1] - rp[vk];
        }
        inv[m] = (d > 0) ? rsqrtf((float)d) : 0.0f;
    }
}

// ---------------- prescale: y = bf16(inv_src * x_src) ----------------

__global__ void prescale_kernel(const float* __restrict__ x, const float* __restrict__ inv,
                                __hip_bfloat16* __restrict__ y, int total) {
    int i = blockIdx.x * blockDim.x + threadIdx.x;
    if (i < total) {
        int node = i >> 6;
        y[i] = __float2bfloat16(inv[node] * x[i]);
    }
}

// ---------------- phase-major gather, 4 edges per wave-instruction ----------------
// wave = 4 groups x 16 lanes; group g handles edge (base+g); lane loads 8B = 4 bf16 cols.
// float4 register accumulator per run; 4 fire-and-forget LDS ds_add_f32 per run end.

template <int G, int NPH>
__global__ __launch_bounds__(256, 8) void gather_kernel_t(
        const int* __restrict__ rp, const int* __restrict__ pay,
        const float* __restrict__ inv_dst,
        const __hip_bfloat16* __restrict__ y_src,
        const float* __restrict__ x_dst,
        float* __restrict__ res) {
    __shared__ float accL[4 * G * DD];
    int wslot = threadIdx.x >> 6;
    int lane = threadIdx.x & 63;
    int grp = lane >> 4;              // 0..3: which edge of the 4-edge step
    int q   = lane & 15;              // 0..15: column quad within the row
    int W = blockIdx.x * 4 + wslot;   // group id (grid sized exactly)
    float* myacc = &accL[wslot * G * DD];
    for (int i = lane; i < G * DD; i += 64) myacc[i] = 0.0f;   // wave-private region

    const char* ybq = (const char*)y_src + (q << 3);   // + q*8 bytes (4 bf16 cols)

    int rr = 0;
    if (lane <= G) rr = rp[(W * NPH) * G + lane];
    for (int h = 0; h < NPH; h++) {
        int rrn = 0;
        if (h + 1 < NPH && lane <= G) rrn = rp[(W * NPH + h + 1) * G + lane];   // prefetch
        for (int i = 0; i < G; i++) {
            int s = __shfl(rr, i, 64);
            int e = __shfl(rr, i + 1, 64);
            if (s == e) continue;
            float r0 = 0.f, r1 = 0.f, r2 = 0.f, r3 = 0.f;
            for (int c = s; c < e; c += 64) {
                int cnt = min(e - c, 64);
                int pvec = (lane < cnt) ? pay[c + lane] : 0;
                for (int t = 0; t < cnt; t += 8) {
                    int pA = __shfl(pvec, t + grp, 64);          // edge c+t+grp
                    int pB = __shfl(pvec, (t + 4 + grp) & 63, 64); // edge c+t+4+grp
                    float wA = (t + grp < cnt) ? 1.0f : 0.0f;
                    float wB = (t + 4 + grp < cnt) ? 1.0f : 0.0f;
                    uint2 dA = *(const uint2*)(ybq + ((size_t)(unsigned)pA << 7));
                    uint2 dB = *(const uint2*)(ybq + ((size_t)(unsigned)pB << 7));
                    float a0 = __uint_as_float(dA.x << 16);
                    float a1 = __uint_as_float(dA.x & 0xffff0000u);
                    float a2 = __uint_as_float(dA.y << 16);
                    float a3 = __uint_as_float(dA.y & 0xffff0000u);
                    float b0 = __uint_as_float(dB.x << 16);
                    float b1 = __uint_as_float(dB.x & 0xffff0000u);
                    float b2 = __uint_as_float(dB.y << 16);
                    float b3 = __uint_as_float(dB.y & 0xffff0000u);
                    r0 = fmaf(a0, wA, r0); r1 = fmaf(a1, wA, r1);
                    r2 = fmaf(a2, wA, r2); r3 = fmaf(a3, wA, r3);
                    r0 = fmaf(b0, wB, r0); r1 = fmaf(b1, wB, r1);
                    r2 = fmaf(b2, wB, r2); r3 = fmaf(b3, wB, r3);
                }
            }
            float* ap = &myacc[i * DD + (q << 2)];
            atomicAdd(ap + 0, r0);      // ds_add_f32, no return; once per run
            atomicAdd(ap + 1, r1);
            atomicAdd(ap + 2, r2);
            atomicAdd(ap + 3, r3);
        }
        rr = rrn;
    }

    int g0 = W * G;
    for (int i = 0; i < G; i++) {
        int n = g0 + i;
        int o = n * DD + lane;
        res[o] = x_dst[o] + COEF * inv_dst[n] * myacc[i * DD + lane];
    }
}

// ---------------- score ----------------

__global__ void score_kernel(const int* __restrict__ lm, const int* __restrict__ lu,
                             const float* __restrict__ ru, const float* __restrict__ rm,
                             float* __restrict__ scores) {
    int tid = blockIdx.x * blockDim.x + threadIdx.x;
    int l = tid >> 6;
    int d = threadIdx.x & 63;
    if (l < NL) {
        int u = lu[l];
        int m = lm[l];
        float v = ru[u * DD + d] * rm[m * DD + d];
        #pragma unroll
        for (int off = 32; off >= 1; off >>= 1)
            v += __shfl_down(v, off, 64);
        if (d == 0) scores[l] = v;
    }
}

// ---------------- fallback: atomic agg path ----------------

__global__ void degree_kernel_f(const int* __restrict__ ef, const int* __restrict__ et,
                                float* __restrict__ deg_m, float* __restrict__ deg_u) {
    int i = blockIdx.x * blockDim.x + threadIdx.x;
    if (i < NE) {
        atomicAdd(&deg_m[ef[i]], 1.0f);
        atomicAdd(&deg_u[et[i]], 1.0f);
    }
}

__global__ void inv_kernel_f(float* __restrict__ deg, int n) {
    int i = blockIdx.x * blockDim.x + threadIdx.x;
    if (i < n) {
        float d = deg[i];
        deg[i] = (d > 0.0f) ? (1.0f / sqrtf(d)) : 0.0f;
    }
}

__global__ void agg_kernel_f(const int* __restrict__ ef, const int* __restrict__ et,
                             const float* __restrict__ inv_m, const float* __restrict__ inv_u,
                             const float* __restrict__ x_u, const float* __restrict__ x_m,
                             float* __restrict__ res_u, float* __restrict__ res_m) {
    int tid = blockIdx.x * blockDim.x + threadIdx.x;
    int e = tid >> 6;
    int d = tid & 63;
    if (e < NE) {
        int f = ef[e];
        int t = et[e];
        float norm = inv_m[f] * inv_u[t] * COEF;
        atomicAdd(&res_u[t * DD + d], norm * x_m[f * DD + d]);
        atomicAdd(&res_m[f * DD + d], norm * x_u[t * DD + d]);
    }
}

__global__ void add_base_kernel_f(const float* __restrict__ xu, const float* __restrict__ xm,
                                  float* __restrict__ ru, float* __restrict__ rm) {
    int i = blockIdx.x * blockDim.x + threadIdx.x;
    const int nu = NU * DD;
    const int nm = NM * DD;
    if (i < nu) {
        ru[i] += xu[i];
    } else if (i < nu + nm) {
        int j = i - nu;
        rm[j] += xm[j];
    }
}

// ---------------- launch ----------------

extern "C" void kernel_launch(void* const* d_in, const int* in_sizes, int n_in,
                              void* d_out, int out_size, void* d_ws, size_t ws_size,
                              hipStream_t stream) {
    const float* emb_user  = (const float*)d_in[0];
    const float* emb_movie = (const float*)d_in[1];
    const int* edge_from   = (const int*)d_in[4];
    const int* edge_to     = (const int*)d_in[5];
    const int* label_movie = (const int*)d_in[6];
    const int* label_user  = (const int*)d_in[7];

    float* out    = (float*)d_out;
    float* scores = out;                              // [NL]
    float* res_u  = out + NL;                         // [NU*DD]
    float* res_m  = out + NL + (size_t)NU * DD;       // [NM*DD]

    // ws layout
    int*   gbh_u  = (int*)d_ws;                       // NBK_U (zeroed)
    int*   gbh_m  = gbh_u + NBK_U;                    // NBK_M (zeroed)
    int*   bo_u   = gbh_m + NBK_M;                    // NBK_U+1
    int*   bcur_u = bo_u + NBK_U + 1;                 // NBK_U
    int*   bo_m   = bcur_u + NBK_U;                   // NBK_M+1
    int*   bcur_m = bo_m + NBK_M + 1;                 // NBK_M
    float* inv_u  = (float*)(bcur_m + NBK_M);         // NU
    float* inv_m  = inv_u + NU;                       // NM
    int*   rp_u   = (int*)(inv_m + NM);               // NVK_U+1
    int*   rp_m   = rp_u + NVK_U + 1;                 // NVK_M+1
    int*   pay_u  = rp_m + NVK_M + 1;                 // NE
    int*   pay_m  = pay_u + NE;                       // NE
    // union region: stage (NE ints, dead after builds) then y_u/y_m (bf16)
    int*   ureg   = pay_m + NE;
    int*   stage  = ureg;                             // NE ints
    __hip_bfloat16* y_u = (__hip_bfloat16*)ureg;                      // NU*DD bf16
    __hip_bfloat16* y_m = (__hip_bfloat16*)(ureg + (size_t)NU * DD / 2); // NM*DD bf16

    size_t ysz    = (size_t)(NU + NM) * DD / 2;       // ints for y region
    size_t uni    = (size_t)NE > ysz ? (size_t)NE : ysz;
    size_t needed = ((size_t)(ureg - (int*)d_ws) + uni) * sizeof(int);

    if (ws_size >= needed) {
        hipMemsetAsync(gbh_u, 0, (size_t)(NBK_U + NBK_M) * sizeof(int), stream);

        bucket_count_kernel<<<(NE / CEC + 255) / 256, 256, 0, stream>>>(
            edge_from, edge_to, gbh_u, gbh_m);
        scan_small_kernel<<<1, 256, 0, stream>>>(gbh_u, bo_u, bcur_u, NBK_U);
        scan_small_kernel<<<1, 256, 0, stream>>>(gbh_m, bo_m, bcur_m, NBK_M);

        // u-side: dest = user (edge_to), src = movie (edge_from)
        partition_kernel<<<(NE / PEC + 255) / 256, 256, 0, stream>>>(
            edge_to, edge_from, bcur_u, stage, NBK_U, VB_U, 0);
        build_kernel<<<NBK_U, 256, 0, stream>>>(stage, bo_u, rp_u, pay_u, NVK_U, VB_U);

        // m-side: dest = movie (edge_from), src = user (edge_to)
        partition_kernel<<<(NE / PEC + 255) / 256, 256, 0, stream>>>(
            edge_from, edge_to, bcur_m, stage, NBK_M, VB_M, 1);
        build_kernel<<<NBK_M, 256, 0, stream>>>(stage, bo_m, rp_m, pay_m, NVK_M, VB_M);

        // inv from rp run-length sums
        inv_u_kernel<<<(NU + 255) / 256, 256, 0, stream>>>(rp_u, inv_u);
        inv_m_kernel<<<(NM + 255) / 256, 256, 0, stream>>>(rp_m, inv_m);

        // prescale (stage is dead now; y overlays it)
        prescale_kernel<<<((size_t)NU * DD + 255) / 256, 256, 0, stream>>>(
            emb_user, inv_u, y_u, NU * DD);
        prescale_kernel<<<((size_t)NM * DD + 255) / 256, 256, 0, stream>>>(
            emb_movie, inv_m, y_m, NM * DD);

        gather_kernel_t<GU, NPH_U><<<NGRP_U / 4, 256, 0, stream>>>(
            rp_u, pay_u, inv_u, y_m, emb_user, res_u);
        gather_kernel_t<GM, NPH_M><<<NGRP_M / 4, 256, 0, stream>>>(
            rp_m, pay_m, inv_m, y_u, emb_movie, res_m);
    } else {
        // ---- fallback: atomic path ----
        float* fdeg_u = (float*)d_ws;
        float* fdeg_m = fdeg_u + NU;
        hipMemsetAsync(res_u, 0, (size_t)(NU + NM) * DD * sizeof(float), stream);
        hipMemsetAsync(fdeg_u, 0, (size_t)(NU + NM) * sizeof(float), stream);
        degree_kernel_f<<<(NE + 255) / 256, 256, 0, stream>>>(edge_from, edge_to, fdeg_m, fdeg_u);
        inv_kernel_f<<<(NU + NM + 255) / 256, 256, 0, stream>>>(fdeg_u, NU + NM);
        agg_kernel_f<<<((size_t)NE * 64 + 255) / 256, 256, 0, stream>>>(
            edge_from, edge_to, fdeg_m, fdeg_u, emb_user, emb_movie, res_u, res_m);
        add_base_kernel_f<<<((NU + NM) * DD + 255) / 256, 256, 0, stream>>>(
            emb_user, emb_movie, res_u, res_m);
    }

    score_kernel<<<((size_t)NL * 64 + 255) / 256, 256, 0, stream>>>(
        label_movie, label_user, res_u, res_m, scores);
}

// Round 7
// 1712.941 us; speedup vs baseline: 1.3031x; 1.3031x over previous
//
#include <hip/hip_runtime.h>
#include <hip/hip_bf16.h>

#define NU 160000
#define NM 60000
#define DD 64
#define NE 5000000
#define NL 200000

// res = x + (1/2 + 1/3 + 1/4) * agg = x + (13/12)*agg  (all layers propagate layer-0)
#define COEF (13.0f / 12.0f)

// ---------------- degree histogram (both sides fused; fire-and-forget atomics) ----------------

#define CEC 16   // edges/thread

__global__ void deg_kernel(const int* __restrict__ ef, const int* __restrict__ et,
                           int* __restrict__ deg_m, int* __restrict__ deg_u) {
    int base = (blockIdx.x * 256 + threadIdx.x) * CEC;
    if (base < NE) {   // NE % 16 == 0 -> all-or-none
        const int4* f4 = (const int4*)(ef + base);
        const int4* t4 = (const int4*)(et + base);
        #pragma unroll
        for (int q = 0; q < CEC / 4; q++) {
            int4 ff = f4[q]; int4 tt = t4[q];
            atomicAdd(&deg_m[ff.x], 1); atomicAdd(&deg_u[tt.x], 1);
            atomicAdd(&deg_m[ff.y], 1); atomicAdd(&deg_u[tt.y], 1);
            atomicAdd(&deg_m[ff.z], 1); atomicAdd(&deg_u[tt.z], 1);
            atomicAdd(&deg_m[ff.w], 1); atomicAdd(&deg_u[tt.w], 1);
        }
    }
}

// ---------------- scans ----------------
// tile_scan: per-1024-element block exclusive scan -> rp partial; block total -> tsum[b]

__global__ void tile_scan_kernel(const int* __restrict__ in, int* __restrict__ rp,
                                 int* __restrict__ tsum, int n) {
    __shared__ int buf[256];
    int tid = threadIdx.x;
    int base = blockIdx.x * 1024;
    int idx = base + tid * 4;
    int v0 = (idx + 0 < n) ? in[idx + 0] : 0;
    int v1 = (idx + 1 < n) ? in[idx + 1] : 0;
    int v2 = (idx + 2 < n) ? in[idx + 2] : 0;
    int v3 = (idx + 3 < n) ? in[idx + 3] : 0;
    int s = v0 + v1 + v2 + v3;
    buf[tid] = s;
    __syncthreads();
    for (int off = 1; off < 256; off <<= 1) {
        int t = (tid >= off) ? buf[tid - off] : 0;
        __syncthreads();
        buf[tid] += t;
        __syncthreads();
    }
    int p = buf[tid] - s;
    if (idx + 0 < n) { rp[idx + 0] = p; p += v0; }
    if (idx + 1 < n) { rp[idx + 1] = p; p += v1; }
    if (idx + 2 < n) { rp[idx + 2] = p; p += v2; }
    if (idx + 3 < n) { rp[idx + 3] = p; }
    if (tid == 255) tsum[blockIdx.x] = buf[255];
}

// small exclusive scan (n <= 1024); out[n]=total

__global__ void scan_small_kernel(const int* __restrict__ in, int* __restrict__ out, int n) {
    __shared__ int buf[256];
    int tid = threadIdx.x;
    int idx = tid * 4;
    int v0 = (idx + 0 < n) ? in[idx + 0] : 0;
    int v1 = (idx + 1 < n) ? in[idx + 1] : 0;
    int v2 = (idx + 2 < n) ? in[idx + 2] : 0;
    int v3 = (idx + 3 < n) ? in[idx + 3] : 0;
    int s = v0 + v1 + v2 + v3;
    buf[tid] = s;
    __syncthreads();
    for (int off = 1; off < 256; off <<= 1) {
        int t = (tid >= off) ? buf[tid - off] : 0;
        __syncthreads();
        buf[tid] += t;
        __syncthreads();
    }
    int p = buf[tid] - s;
    if (idx + 0 < n) { out[idx + 0] = p; p += v0; }
    if (idx + 1 < n) { out[idx + 1] = p; p += v1; }
    if (idx + 2 < n) { out[idx + 2] = p; p += v2; }
    if (idx + 3 < n) { out[idx + 3] = p; p += v3; }
    if (tid == 255) out[n] = buf[255];
}

// scan_add: rp[i] += toff[tile]; cur[i] = rp[i]; inv[i] = rsqrt(deg[i]); rp[n] = NE

__global__ void scan_add_kernel(int* __restrict__ rp, const int* __restrict__ toff,
                                const int* __restrict__ deg, float* __restrict__ inv,
                                int* __restrict__ cur, int n) {
    int i = blockIdx.x * blockDim.x + threadIdx.x;
    if (i < n) {
        int r = rp[i] + toff[i >> 10];
        rp[i] = r;
        cur[i] = r;
        int d = deg[i];
        inv[i] = (d > 0) ? rsqrtf((float)d) : 0.0f;
        if (i == 0) rp[n] = NE;
    }
}

// ---------------- placement: pos = atomicAdd(cur[dest]); pay[pos] = src (both sides) ----------------

__global__ void place_kernel(const int* __restrict__ ef, const int* __restrict__ et,
                             int* __restrict__ cur_u, int* __restrict__ cur_m,
                             int* __restrict__ pay_u, int* __restrict__ pay_m) {
    int base = (blockIdx.x * 256 + threadIdx.x) * CEC;
    if (base < NE) {
        const int4* f4 = (const int4*)(ef + base);
        const int4* t4 = (const int4*)(et + base);
        #pragma unroll
        for (int q = 0; q < CEC / 4; q++) {
            int4 ff = f4[q]; int4 tt = t4[q];
            int p;
            p = atomicAdd(&cur_u[tt.x], 1); pay_u[p] = ff.x;
            p = atomicAdd(&cur_m[ff.x], 1); pay_m[p] = tt.x;
            p = atomicAdd(&cur_u[tt.y], 1); pay_u[p] = ff.y;
            p = atomicAdd(&cur_m[ff.y], 1); pay_m[p] = tt.y;
            p = atomicAdd(&cur_u[tt.z], 1); pay_u[p] = ff.z;
            p = atomicAdd(&cur_m[ff.z], 1); pay_m[p] = tt.z;
            p = atomicAdd(&cur_u[tt.w], 1); pay_u[p] = ff.w;
            p = atomicAdd(&cur_m[ff.w], 1); pay_m[p] = tt.w;
        }
    }
}

// ---------------- prescale: y = bf16(inv_src * x_src) ----------------

__global__ void prescale_kernel(const float* __restrict__ x, const float* __restrict__ inv,
                                __hip_bfloat16* __restrict__ y, int total) {
    int i = blockIdx.x * blockDim.x + threadIdx.x;
    if (i < total) {
        int node = i >> 6;
        y[i] = __float2bfloat16(inv[node] * x[i]);
    }
}

// ---------------- gather (round-0 proven form: one wave per node, 4-deep batched loads) ----------------

__global__ void gather_kernel(const int* __restrict__ rp, const int* __restrict__ pay,
                              const float* __restrict__ inv_dst,
                              const __hip_bfloat16* __restrict__ y_src,
                              const float* __restrict__ x_dst,
                              float* __restrict__ res, int n) {
    int tid = blockIdx.x * blockDim.x + threadIdx.x;
    int node = tid >> 6;
    int lane = threadIdx.x & 63;
    if (node >= n) return;
    int start = rp[node];
    int end   = rp[node + 1];
    float acc = 0.0f;
    for (int i = start; i < end; i += 64) {
        int cnt = min(end - i, 64);
        int nid = (lane < cnt) ? pay[i + lane] : 0;
        int j = 0;
        for (; j + 4 <= cnt; j += 4) {
            int f0 = __shfl(nid, j + 0, 64);
            int f1 = __shfl(nid, j + 1, 64);
            int f2 = __shfl(nid, j + 2, 64);
            int f3 = __shfl(nid, j + 3, 64);
            float a0 = __bfloat162float(y_src[f0 * DD + lane]);
            float a1 = __bfloat162float(y_src[f1 * DD + lane]);
            float a2 = __bfloat162float(y_src[f2 * DD + lane]);
            float a3 = __bfloat162float(y_src[f3 * DD + lane]);
            acc += a0 + a1 + a2 + a3;
        }
        for (; j < cnt; j++) {
            int f0 = __shfl(nid, j, 64);
            acc += __bfloat162float(y_src[f0 * DD + lane]);
        }
    }
    int o = node * DD + lane;
    res[o] = x_dst[o] + COEF * inv_dst[node] * acc;
}

// ---------------- score ----------------

__global__ void score_kernel(const int* __restrict__ lm, const int* __restrict__ lu,
                             const float* __restrict__ ru, const float* __restrict__ rm,
                             float* __restrict__ scores) {
    int tid = blockIdx.x * blockDim.x + threadIdx.x;
    int l = tid >> 6;
    int d = threadIdx.x & 63;
    if (l < NL) {
        int u = lu[l];
        int m = lm[l];
        float v = ru[u * DD + d] * rm[m * DD + d];
        #pragma unroll
        for (int off = 32; off >= 1; off >>= 1)
            v += __shfl_down(v, off, 64);
        if (d == 0) scores[l] = v;
    }
}

// ---------------- fallback: atomic agg path ----------------

__global__ void degree_kernel_f(const int* __restrict__ ef, const int* __restrict__ et,
                                float* __restrict__ deg_m, float* __restrict__ deg_u) {
    int i = blockIdx.x * blockDim.x + threadIdx.x;
    if (i < NE) {
        atomicAdd(&deg_m[ef[i]], 1.0f);
        atomicAdd(&deg_u[et[i]], 1.0f);
    }
}

__global__ void inv_kernel_f(float* __restrict__ deg, int n) {
    int i = blockIdx.x * blockDim.x + threadIdx.x;
    if (i < n) {
        float d = deg[i];
        deg[i] = (d > 0.0f) ? (1.0f / sqrtf(d)) : 0.0f;
    }
}

__global__ void agg_kernel_f(const int* __restrict__ ef, const int* __restrict__ et,
                             const float* __restrict__ inv_m, const float* __restrict__ inv_u,
                             const float* __restrict__ x_u, const float* __restrict__ x_m,
                             float* __restrict__ res_u, float* __restrict__ res_m) {
    int tid = blockIdx.x * blockDim.x + threadIdx.x;
    int e = tid >> 6;
    int d = tid & 63;
    if (e < NE) {
        int f = ef[e];
        int t = et[e];
        float norm = inv_m[f] * inv_u[t] * COEF;
        atomicAdd(&res_u[t * DD + d], norm * x_m[f * DD + d]);
        atomicAdd(&res_m[f * DD + d], norm * x_u[t * DD + d]);
    }
}

__global__ void add_base_kernel_f(const float* __restrict__ xu, const float* __restrict__ xm,
                                  float* __restrict__ ru, float* __restrict__ rm) {
    int i = blockIdx.x * blockDim.x + threadIdx.x;
    const int nu = NU * DD;
    const int nm = NM * DD;
    if (i < nu) {
        ru[i] += xu[i];
    } else if (i < nu + nm) {
        int j = i - nu;
        rm[j] += xm[j];
    }
}

// ---------------- launch ----------------

extern "C" void kernel_launch(void* const* d_in, const int* in_sizes, int n_in,
                              void* d_out, int out_size, void* d_ws, size_t ws_size,
                              hipStream_t stream) {
    const float* emb_user  = (const float*)d_in[0];
    const float* emb_movie = (const float*)d_in[1];
    const int* edge_from   = (const int*)d_in[4];
    const int* edge_to     = (const int*)d_in[5];
    const int* label_movie = (const int*)d_in[6];
    const int* label_user  = (const int*)d_in[7];

    float* out    = (float*)d_out;
    float* scores = out;                              // [NL]
    float* res_u  = out + NL;                         // [NU*DD]
    float* res_m  = out + NL + (size_t)NU * DD;       // [NM*DD]

    const int NTU = (NU + 1023) >> 10;   // 157 tiles
    const int NTM = (NM + 1023) >> 10;   // 59 tiles

    // ws layout
    int*   deg_u  = (int*)d_ws;                       // NU   (zeroed)
    int*   deg_m  = deg_u + NU;                       // NM   (zeroed)
    int*   rp_u   = deg_m + NM;                       // NU+1
    int*   rp_m   = rp_u + NU + 1;                    // NM+1
    int*   cur_u  = rp_m + NM + 1;                    // NU
    int*   cur_m  = cur_u + NU;                       // NM
    int*   tsum_u = cur_m + NM;                       // NTU
    int*   toff_u = tsum_u + NTU;                     // NTU+1
    int*   tsum_m = toff_u + NTU + 1;                 // NTM
    int*   toff_m = tsum_m + NTM;                     // NTM+1
    float* inv_u  = (float*)(toff_m + NTM + 1);       // NU
    float* inv_m  = inv_u + NU;                       // NM
    int*   pay_u  = (int*)(inv_m + NM);               // NE
    int*   pay_m  = pay_u + NE;                       // NE
    __hip_bfloat16* y_u = (__hip_bfloat16*)(pay_m + NE);              // NU*DD bf16
    __hip_bfloat16* y_m = y_u + (size_t)NU * DD;                      // NM*DD bf16

    size_t ysz    = (size_t)(NU + NM) * DD / 2;       // ints for y region
    size_t needed = ((size_t)((int*)y_u - (int*)d_ws) + ysz) * sizeof(int);

    if (ws_size >= needed) {
        hipMemsetAsync(deg_u, 0, (size_t)(NU + NM) * sizeof(int), stream);

        deg_kernel<<<(NE / CEC + 255) / 256, 256, 0, stream>>>(
            edge_from, edge_to, deg_m, deg_u);

        tile_scan_kernel<<<NTU, 256, 0, stream>>>(deg_u, rp_u, tsum_u, NU);
        tile_scan_kernel<<<NTM, 256, 0, stream>>>(deg_m, rp_m, tsum_m, NM);
        scan_small_kernel<<<1, 256, 0, stream>>>(tsum_u, toff_u, NTU);
        scan_small_kernel<<<1, 256, 0, stream>>>(tsum_m, toff_m, NTM);
        scan_add_kernel<<<(NU + 255) / 256, 256, 0, stream>>>(rp_u, toff_u, deg_u, inv_u, cur_u, NU);
        scan_add_kernel<<<(NM + 255) / 256, 256, 0, stream>>>(rp_m, toff_m, deg_m, inv_m, cur_m, NM);

        place_kernel<<<(NE / CEC + 255) / 256, 256, 0, stream>>>(
            edge_from, edge_to, cur_u, cur_m, pay_u, pay_m);

        prescale_kernel<<<((size_t)NU * DD + 255) / 256, 256, 0, stream>>>(
            emb_user, inv_u, y_u, NU * DD);
        prescale_kernel<<<((size_t)NM * DD + 255) / 256, 256, 0, stream>>>(
            emb_movie, inv_m, y_m, NM * DD);

        gather_kernel<<<((size_t)NU * 64 + 255) / 256, 256, 0, stream>>>(
            rp_u, pay_u, inv_u, y_m, emb_user, res_u, NU);
        gather_kernel<<<((size_t)NM * 64 + 255) / 256, 256, 0, stream>>>(
            rp_m, pay_m, inv_m, y_u, emb_movie, res_m, NM);
    } else {
        // ---- fallback: atomic path ----
        float* fdeg_u = (float*)d_ws;
        float* fdeg_m = fdeg_u + NU;
        hipMemsetAsync(res_u, 0, (size_t)(NU + NM) * DD * sizeof(float), stream);
        hipMemsetAsync(fdeg_u, 0, (size_t)(NU + NM) * sizeof(float), stream);
        degree_kernel_f<<<(NE + 255) / 256, 256, 0, stream>>>(edge_from, edge_to, fdeg_m, fdeg_u);
        inv_kernel_f<<<(NU + NM + 255) / 256, 256, 0, stream>>>(fdeg_u, NU + NM);
        agg_kernel_f<<<((size_t)NE * 64 + 255) / 256, 256, 0, stream>>>(
            edge_from, edge_to, fdeg_m, fdeg_u, emb_user, emb_movie, res_u, res_m);
        add_base_kernel_f<<<((NU + NM) * DD + 255) / 256, 256, 0, stream>>>(
            emb_user, emb_movie, res_u, res_m);
    }

    score_kernel<<<((size_t)NL * 64 + 255) / 256, 256, 0, stream>>>(
        label_movie, label_user, res_u, res_m, scores);
}

// Round 8
// 1107.941 us; speedup vs baseline: 2.0147x; 1.5461x over previous
//
#include <hip/hip_runtime.h>
#include <hip/hip_bf16.h>

#define NU 160000
#define NM 60000
#define DD 64
#define NE 5000000
#define NL 200000

// res = x + (1/2 + 1/3 + 1/4) * agg = x + (13/12)*agg  (all layers propagate layer-0)
#define COEF (13.0f / 12.0f)

// bucket shifts for partition/build-lite
#define SH_U 7                    // 128 users/bucket
#define SH_M 5                    // 32 movies/bucket
#define NBU2 (NU >> SH_U)         // 1250 buckets (exact)
#define NBM2 (NM >> SH_M)         // 1875 buckets (exact)
#define VB_U 16                   // movie id fits 16 bits
#define VB_M 18                   // user id fits 18 bits

#define CEC 16   // edges/thread in streaming kernels

// ---------------- degree histogram (both sides fused; fire-and-forget atomics) ----------------

__global__ void deg_kernel(const int* __restrict__ ef, const int* __restrict__ et,
                           int* __restrict__ deg_m, int* __restrict__ deg_u) {
    int base = (blockIdx.x * 256 + threadIdx.x) * CEC;
    if (base < NE) {   // NE % 16 == 0 -> all-or-none
        const int4* f4 = (const int4*)(ef + base);
        const int4* t4 = (const int4*)(et + base);
        #pragma unroll
        for (int q = 0; q < CEC / 4; q++) {
            int4 ff = f4[q]; int4 tt = t4[q];
            atomicAdd(&deg_m[ff.x], 1); atomicAdd(&deg_u[tt.x], 1);
            atomicAdd(&deg_m[ff.y], 1); atomicAdd(&deg_u[tt.y], 1);
            atomicAdd(&deg_m[ff.z], 1); atomicAdd(&deg_u[tt.z], 1);
            atomicAdd(&deg_m[ff.w], 1); atomicAdd(&deg_u[tt.w], 1);
        }
    }
}

// ---------------- scans ----------------
// tile_scan: per-1024-element block exclusive scan -> rp partial; block total -> tsum[b]

__global__ void tile_scan_kernel(const int* __restrict__ in, int* __restrict__ rp,
                                 int* __restrict__ tsum, int n) {
    __shared__ int buf[256];
    int tid = threadIdx.x;
    int base = blockIdx.x * 1024;
    int idx = base + tid * 4;
    int v0 = (idx + 0 < n) ? in[idx + 0] : 0;
    int v1 = (idx + 1 < n) ? in[idx + 1] : 0;
    int v2 = (idx + 2 < n) ? in[idx + 2] : 0;
    int v3 = (idx + 3 < n) ? in[idx + 3] : 0;
    int s = v0 + v1 + v2 + v3;
    buf[tid] = s;
    __syncthreads();
    for (int off = 1; off < 256; off <<= 1) {
        int t = (tid >= off) ? buf[tid - off] : 0;
        __syncthreads();
        buf[tid] += t;
        __syncthreads();
    }
    int p = buf[tid] - s;
    if (idx + 0 < n) { rp[idx + 0] = p; p += v0; }
    if (idx + 1 < n) { rp[idx + 1] = p; p += v1; }
    if (idx + 2 < n) { rp[idx + 2] = p; p += v2; }
    if (idx + 3 < n) { rp[idx + 3] = p; }
    if (tid == 255) tsum[blockIdx.x] = buf[255];
}

// small exclusive scan (n <= 1024); out[n]=total

__global__ void scan_small_kernel(const int* __restrict__ in, int* __restrict__ out, int n) {
    __shared__ int buf[256];
    int tid = threadIdx.x;
    int idx = tid * 4;
    int v0 = (idx + 0 < n) ? in[idx + 0] : 0;
    int v1 = (idx + 1 < n) ? in[idx + 1] : 0;
    int v2 = (idx + 2 < n) ? in[idx + 2] : 0;
    int v3 = (idx + 3 < n) ? in[idx + 3] : 0;
    int s = v0 + v1 + v2 + v3;
    buf[tid] = s;
    __syncthreads();
    for (int off = 1; off < 256; off <<= 1) {
        int t = (tid >= off) ? buf[tid - off] : 0;
        __syncthreads();
        buf[tid] += t;
        __syncthreads();
    }
    int p = buf[tid] - s;
    if (idx + 0 < n) { out[idx + 0] = p; p += v0; }
    if (idx + 1 < n) { out[idx + 1] = p; p += v1; }
    if (idx + 2 < n) { out[idx + 2] = p; p += v2; }
    if (idx + 3 < n) { out[idx + 3] = p; p += v3; }
    if (tid == 255) out[n] = buf[255];
}

// scan_add: rp[i] += toff[tile]; inv[i] = rsqrt(deg[i]); bcur[b] = rp[b<<bshift]; rp[n] = NE

__global__ void scan_add_kernel(int* __restrict__ rp, const int* __restrict__ toff,
                                const int* __restrict__ deg, float* __restrict__ inv,
                                int* __restrict__ bcur, int n, int bshift) {
    int i = blockIdx.x * blockDim.x + threadIdx.x;
    if (i < n) {
        int r = rp[i] + toff[i >> 10];
        rp[i] = r;
        int d = deg[i];
        inv[i] = (d > 0) ? rsqrtf((float)d) : 0.0f;
        if ((i & ((1 << bshift) - 1)) == 0) bcur[i >> bshift] = r;
        if (i == 0) rp[n] = NE;
    }
}

// ---------------- coarse partition into bucket-grouped staging (packed int32) ----------------
// stage entry = ((dest & mask) << valbits) | src ; bucket = dest >> shift

#define PEC 16   // edges/thread; 4096/block

__global__ void partition_kernel(const int* __restrict__ key, const int* __restrict__ val,
                                 int* __restrict__ bcur, int* __restrict__ stage,
                                 int nb, int shift, int valbits) {
    __shared__ int lh[2048];
    __shared__ int lbase[2048];
    int tid = threadIdx.x;
    int lmask = (1 << shift) - 1;
    for (int i = tid; i < nb; i += 256) lh[i] = 0;
    __syncthreads();
    int base = (blockIdx.x * 256 + tid) * PEC;
    int k_[PEC], v_[PEC], br_[PEC];
    bool act = base < NE;   // NE % 16 == 0 -> all-or-none
    if (act) {
        const int4* k4 = (const int4*)(key + base);
        const int4* v4 = (const int4*)(val + base);
        #pragma unroll
        for (int q = 0; q < PEC / 4; q++) {
            int4 kk = k4[q]; int4 vv = v4[q];
            k_[q * 4 + 0] = kk.x; k_[q * 4 + 1] = kk.y; k_[q * 4 + 2] = kk.z; k_[q * 4 + 3] = kk.w;
            v_[q * 4 + 0] = vv.x; v_[q * 4 + 1] = vv.y; v_[q * 4 + 2] = vv.z; v_[q * 4 + 3] = vv.w;
        }
        #pragma unroll
        for (int q = 0; q < PEC; q++) {
            int b = k_[q] >> shift;
            int r = atomicAdd(&lh[b], 1);       // rank within (block,bucket) < 4096
            br_[q] = (b << 13) | r;
        }
    }
    __syncthreads();
    for (int i = tid; i < nb; i += 256) lbase[i] = lh[i] ? atomicAdd(&bcur[i], lh[i]) : 0;
    __syncthreads();
    if (act) {
        #pragma unroll
        for (int q = 0; q < PEC; q++) {
            int b = br_[q] >> 13;
            int r = br_[q] & 8191;
            stage[lbase[b] + r] = ((k_[q] & lmask) << valbits) | v_[q];
        }
    }
}

// ---------------- build-lite: per-bucket placement, cursors straight from rp ----------------

__global__ void build_lite_kernel(const int* __restrict__ stage, const int* __restrict__ rp,
                                  int* __restrict__ pay, int shift, int valbits) {
    __shared__ int cur[128];
    int b = blockIdx.x;
    int tid = threadIdx.x;
    int bs = 1 << shift;
    int base = b << shift;
    if (tid < bs) cur[tid] = rp[base + tid];
    __syncthreads();
    int s0 = rp[base];
    int s1 = rp[base + bs];
    int vmask = (1 << valbits) - 1;
    for (int e = s0 + tid; e < s1; e += 256) {
        int p = stage[e];
        int pos = atomicAdd(&cur[p >> valbits], 1);
        pay[pos] = p & vmask;
    }
}

// ---------------- prescale: y = bf16(inv_src * x_src) ----------------

__global__ void prescale_kernel(const float* __restrict__ x, const float* __restrict__ inv,
                                __hip_bfloat16* __restrict__ y, int total) {
    int i = blockIdx.x * blockDim.x + threadIdx.x;
    if (i < total) {
        int node = i >> 6;
        y[i] = __float2bfloat16(inv[node] * x[i]);
    }
}

// ---------------- gather (round-0 proven form: one wave per node, 4-deep batched loads) ----------------

__global__ void gather_kernel(const int* __restrict__ rp, const int* __restrict__ pay,
                              const float* __restrict__ inv_dst,
                              const __hip_bfloat16* __restrict__ y_src,
                              const float* __restrict__ x_dst,
                              float* __restrict__ res, int n) {
    int tid = blockIdx.x * blockDim.x + threadIdx.x;
    int node = tid >> 6;
    int lane = threadIdx.x & 63;
    if (node >= n) return;
    int start = rp[node];
    int end   = rp[node + 1];
    float acc = 0.0f;
    for (int i = start; i < end; i += 64) {
        int cnt = min(end - i, 64);
        int nid = (lane < cnt) ? pay[i + lane] : 0;
        int j = 0;
        for (; j + 4 <= cnt; j += 4) {
            int f0 = __shfl(nid, j + 0, 64);
            int f1 = __shfl(nid, j + 1, 64);
            int f2 = __shfl(nid, j + 2, 64);
            int f3 = __shfl(nid, j + 3, 64);
            float a0 = __bfloat162float(y_src[f0 * DD + lane]);
            float a1 = __bfloat162float(y_src[f1 * DD + lane]);
            float a2 = __bfloat162float(y_src[f2 * DD + lane]);
            float a3 = __bfloat162float(y_src[f3 * DD + lane]);
            acc += a0 + a1 + a2 + a3;
        }
        for (; j < cnt; j++) {
            int f0 = __shfl(nid, j, 64);
            acc += __bfloat162float(y_src[f0 * DD + lane]);
        }
    }
    int o = node * DD + lane;
    res[o] = x_dst[o] + COEF * inv_dst[node] * acc;
}

// ---------------- score ----------------

__global__ void score_kernel(const int* __restrict__ lm, const int* __restrict__ lu,
                             const float* __restrict__ ru, const float* __restrict__ rm,
                             float* __restrict__ scores) {
    int tid = blockIdx.x * blockDim.x + threadIdx.x;
    int l = tid >> 6;
    int d = threadIdx.x & 63;
    if (l < NL) {
        int u = lu[l];
        int m = lm[l];
        float v = ru[u * DD + d] * rm[m * DD + d];
        #pragma unroll
        for (int off = 32; off >= 1; off >>= 1)
            v += __shfl_down(v, off, 64);
        if (d == 0) scores[l] = v;
    }
}

// ---------------- fallback: atomic agg path ----------------

__global__ void degree_kernel_f(const int* __restrict__ ef, const int* __restrict__ et,
                                float* __restrict__ deg_m, float* __restrict__ deg_u) {
    int i = blockIdx.x * blockDim.x + threadIdx.x;
    if (i < NE) {
        atomicAdd(&deg_m[ef[i]], 1.0f);
        atomicAdd(&deg_u[et[i]], 1.0f);
    }
}

__global__ void inv_kernel_f(float* __restrict__ deg, int n) {
    int i = blockIdx.x * blockDim.x + threadIdx.x;
    if (i < n) {
        float d = deg[i];
        deg[i] = (d > 0.0f) ? (1.0f / sqrtf(d)) : 0.0f;
    }
}

__global__ void agg_kernel_f(const int* __restrict__ ef, const int* __restrict__ et,
                             const float* __restrict__ inv_m, const float* __restrict__ inv_u,
                             const float* __restrict__ x_u, const float* __restrict__ x_m,
                             float* __restrict__ res_u, float* __restrict__ res_m) {
    int tid = blockIdx.x * blockDim.x + threadIdx.x;
    int e = tid >> 6;
    int d = tid & 63;
    if (e < NE) {
        int f = ef[e];
        int t = et[e];
        float norm = inv_m[f] * inv_u[t] * COEF;
        atomicAdd(&res_u[t * DD + d], norm * x_m[f * DD + d]);
        atomicAdd(&res_m[f * DD + d], norm * x_u[t * DD + d]);
    }
}

__global__ void add_base_kernel_f(const float* __restrict__ xu, const float* __restrict__ xm,
                                  float* __restrict__ ru, float* __restrict__ rm) {
    int i = blockIdx.x * blockDim.x + threadIdx.x;
    const int nu = NU * DD;
    const int nm = NM * DD;
    if (i < nu) {
        ru[i] += xu[i];
    } else if (i < nu + nm) {
        int j = i - nu;
        rm[j] += xm[j];
    }
}

// ---------------- launch ----------------

extern "C" void kernel_launch(void* const* d_in, const int* in_sizes, int n_in,
                              void* d_out, int out_size, void* d_ws, size_t ws_size,
                              hipStream_t stream) {
    const float* emb_user  = (const float*)d_in[0];
    const float* emb_movie = (const float*)d_in[1];
    const int* edge_from   = (const int*)d_in[4];
    const int* edge_to     = (const int*)d_in[5];
    const int* label_movie = (const int*)d_in[6];
    const int* label_user  = (const int*)d_in[7];

    float* out    = (float*)d_out;
    float* scores = out;                              // [NL]
    float* res_u  = out + NL;                         // [NU*DD]
    float* res_m  = out + NL + (size_t)NU * DD;       // [NM*DD]

    const int NTU = (NU + 1023) >> 10;   // 157 tiles
    const int NTM = (NM + 1023) >> 10;   // 59 tiles

    // ws layout
    int*   deg_u  = (int*)d_ws;                       // NU   (zeroed)
    int*   deg_m  = deg_u + NU;                       // NM   (zeroed)
    int*   rp_u   = deg_m + NM;                       // NU+1
    int*   rp_m   = rp_u + NU + 1;                    // NM+1
    int*   tsum_u = rp_m + NM + 1;                    // NTU
    int*   toff_u = tsum_u + NTU;                     // NTU+1
    int*   tsum_m = toff_u + NTU + 1;                 // NTM
    int*   toff_m = tsum_m + NTM;                     // NTM+1
    int*   bcur_u = toff_m + NTM + 1;                 // NBU2
    int*   bcur_m = bcur_u + NBU2;                    // NBM2
    float* inv_u  = (float*)(bcur_m + NBM2);          // NU
    float* inv_m  = inv_u + NU;                       // NM
    int*   pay_u  = (int*)(inv_m + NM);               // NE
    int*   pay_m  = pay_u + NE;                       // NE
    // union region: stage (NE ints, dead after builds) then y_u/y_m (bf16)
    int*   ureg   = pay_m + NE;
    int*   stage  = ureg;                             // NE ints
    __hip_bfloat16* y_u = (__hip_bfloat16*)ureg;                      // NU*DD bf16
    __hip_bfloat16* y_m = (__hip_bfloat16*)(ureg + (size_t)NU * DD / 2); // NM*DD bf16

    size_t ysz    = (size_t)(NU + NM) * DD / 2;       // ints for y region
    size_t uni    = (size_t)NE > ysz ? (size_t)NE : ysz;
    size_t needed = ((size_t)(ureg - (int*)d_ws) + uni) * sizeof(int);

    if (ws_size >= needed) {
        hipMemsetAsync(deg_u, 0, (size_t)(NU + NM) * sizeof(int), stream);

        deg_kernel<<<(NE / CEC + 255) / 256, 256, 0, stream>>>(
            edge_from, edge_to, deg_m, deg_u);

        tile_scan_kernel<<<NTU, 256, 0, stream>>>(deg_u, rp_u, tsum_u, NU);
        tile_scan_kernel<<<NTM, 256, 0, stream>>>(deg_m, rp_m, tsum_m, NM);
        scan_small_kernel<<<1, 256, 0, stream>>>(tsum_u, toff_u, NTU);
        scan_small_kernel<<<1, 256, 0, stream>>>(tsum_m, toff_m, NTM);
        scan_add_kernel<<<(NU + 255) / 256, 256, 0, stream>>>(
            rp_u, toff_u, deg_u, inv_u, bcur_u, NU, SH_U);
        scan_add_kernel<<<(NM + 255) / 256, 256, 0, stream>>>(
            rp_m, toff_m, deg_m, inv_m, bcur_m, NM, SH_M);

        // u-side: dest = user (edge_to), src = movie (edge_from)
        partition_kernel<<<(NE / PEC + 255) / 256, 256, 0, stream>>>(
            edge_to, edge_from, bcur_u, stage, NBU2, SH_U, VB_U);
        build_lite_kernel<<<NBU2, 256, 0, stream>>>(stage, rp_u, pay_u, SH_U, VB_U);

        // m-side: dest = movie (edge_from), src = user (edge_to)
        partition_kernel<<<(NE / PEC + 255) / 256, 256, 0, stream>>>(
            edge_from, edge_to, bcur_m, stage, NBM2, SH_M, VB_M);
        build_lite_kernel<<<NBM2, 256, 0, stream>>>(stage, rp_m, pay_m, SH_M, VB_M);

        // prescale (stage is dead now; y overlays it)
        prescale_kernel<<<((size_t)NU * DD + 255) / 256, 256, 0, stream>>>(
            emb_user, inv_u, y_u, NU * DD);
        prescale_kernel<<<((size_t)NM * DD + 255) / 256, 256, 0, stream>>>(
            emb_movie, inv_m, y_m, NM * DD);

        gather_kernel<<<((size_t)NU * 64 + 255) / 256, 256, 0, stream>>>(
            rp_u, pay_u, inv_u, y_m, emb_user, res_u, NU);
        gather_kernel<<<((size_t)NM * 64 + 255) / 256, 256, 0, stream>>>(
            rp_m, pay_m, inv_m, y_u, emb_movie, res_m, NM);
    } else {
        // ---- fallback: atomic path ----
        float* fdeg_u = (float*)d_ws;
        float* fdeg_m = fdeg_u + NU;
        hipMemsetAsync(res_u, 0, (size_t)(NU + NM) * DD * sizeof(float), stream);
        hipMemsetAsync(fdeg_u, 0, (size_t)(NU + NM) * sizeof(float), stream);
        degree_kernel_f<<<(NE + 255) / 256, 256, 0, stream>>>(edge_from, edge_to, fdeg_m, fdeg_u);
        inv_kernel_f<<<(NU + NM + 255) / 256, 256, 0, stream>>>(fdeg_u, NU + NM);
        agg_kernel_f<<<((size_t)NE * 64 + 255) / 256, 256, 0, stream>>>(
            edge_from, edge_to, fdeg_m, fdeg_u, emb_user, emb_movie, res_u, res_m);
        add_base_kernel_f<<<((NU + NM) * DD + 255) / 256, 256, 0, stream>>>(
            emb_user, emb_movie, res_u, res_m);
    }

    score_kernel<<<((size_t)NL * 64 + 255) / 256, 256, 0, stream>>>(
        label_movie, label_user, res_u, res_m, scores);
}